// Round 19
// baseline (309.058 us; speedup 1.0000x reference)
//
#include <hip/hip_runtime.h>
#include <hip/hip_bf16.h>

typedef _Float16 f16x8 __attribute__((ext_vector_type(8)));
typedef float f32x4 __attribute__((ext_vector_type(4)));
typedef unsigned short u16x4 __attribute__((ext_vector_type(4)));
typedef unsigned short u16x8 __attribute__((ext_vector_type(8)));

__device__ __forceinline__ unsigned short f2h(float f) {
    _Float16 h = (_Float16)f;
    union { _Float16 h; unsigned short u; } v; v.h = h;
    return v.u;
}

// async global->LDS, 16B per lane. LDS dest = wave-uniform base + lane*16.
__device__ __forceinline__ void gload16(const void* g, void* s) {
    __builtin_amdgcn_global_load_lds((const __attribute__((address_space(1))) void*)g,
                                     (__attribute__((address_space(3))) void*)s, 16, 0, 0);
}

// ---------------- zero fp32 buffer ----------------
__global__ __launch_bounds__(256)
void zero_f32(float* __restrict__ p, int n4) {
    int i = blockIdx.x * 256 + threadIdx.x, st = gridDim.x * 256;
    for (; i < n4; i += st)
        reinterpret_cast<float4*>(p)[i] = make_float4(0.f, 0.f, 0.f, 0.f);
}

// ---------------- fp32 -> fp16 convert ----------------
__global__ __launch_bounds__(256)
void cvt_f32_f16(const float* __restrict__ in, unsigned short* __restrict__ out, int n8) {
    int i = blockIdx.x * 256 + threadIdx.x, st = gridDim.x * 256;
    for (; i < n8; i += st) {
        float4 v0 = reinterpret_cast<const float4*>(in)[2 * i];
        float4 v1 = reinterpret_cast<const float4*>(in)[2 * i + 1];
        float a[8] = {v0.x, v0.y, v0.z, v0.w, v1.x, v1.y, v1.z, v1.w};
        u16x8 h;
        #pragma unroll
        for (int j = 0; j < 8; ++j) h[j] = f2h(a[j]);
        reinterpret_cast<u16x8*>(out)[i] = h;
    }
}

// ---------------- W (R x C fp32) -> W^T fp16 (C x R) ----------------
__global__ __launch_bounds__(256)
void transpose_cvt(const float* __restrict__ in, unsigned short* __restrict__ ot,
                   int R, int C) {
    __shared__ float T[64][65];
    const int r0 = blockIdx.y * 64, c0 = blockIdx.x * 64;
    const int t = threadIdx.x;
    const int lr = t >> 2, lcq = (t & 3) * 16;
    #pragma unroll
    for (int q = 0; q < 4; ++q) {
        float4 v = *reinterpret_cast<const float4*>(&in[(long long)(r0 + lr) * C + c0 + lcq + q * 4]);
        T[lr][lcq + q * 4 + 0] = v.x; T[lr][lcq + q * 4 + 1] = v.y;
        T[lr][lcq + q * 4 + 2] = v.z; T[lr][lcq + q * 4 + 3] = v.w;
    }
    __syncthreads();
    const int oc = t >> 2, orq = (t & 3) * 16;
    #pragma unroll
    for (int q = 0; q < 4; ++q) {
        u16x4 hv;
        #pragma unroll
        for (int j = 0; j < 4; ++j) hv[j] = f2h(T[orq + q * 4 + j][oc]);
        long long o = (long long)(c0 + oc) * R + r0 + orq + q * 4;
        *reinterpret_cast<u16x4*>(&ot[o]) = hv;
    }
}

// ============ kernel A: 256x128 tile, 8 waves (64x64 each), 3-buf vmcnt(3) ============
// (measured-best for GEMM1/out: VGPR 60, 72KB LDS -> 2 blocks/CU, 4 waves/SIMD, 115us)
// EPI: 1 f32+bias | 3 QKV (Q^T,K^T LDS transpose + V row-gather)
template<int EPI>
__global__ __launch_bounds__(512)
void gemm_a(const unsigned short* __restrict__ A, const unsigned short* __restrict__ B,
            int sk_shift, int ks_size,
            long long lda, long long ldb,
            long long sA, long long sB, long long sC,
            float* __restrict__ Cf, unsigned short* __restrict__ Ch, long long ldc,
            const float* __restrict__ bias, float scale,
            unsigned short* __restrict__ qt, unsigned short* __restrict__ kt,
            unsigned short* __restrict__ vout)
{
    __shared__ __align__(16) unsigned short SMEM[3][12288];   // 3 x 24KB

    const unsigned int gx = gridDim.x, gy = gridDim.y;
    const unsigned int lin = blockIdx.x + gx * (blockIdx.y + gy * blockIdx.z);
    const unsigned int nwg = gx * gy * gridDim.z;
    const unsigned int sw = (lin & 7u) * (nwg >> 3) + (lin >> 3);
    const int bxi = (int)(sw % gx);
    const int byi = (int)((sw / gx) % gy);
    const int bzi = (int)(sw / (gx * gy));

    const int tid  = threadIdx.x;
    const int wave = tid >> 6, lane = tid & 63;
    const int m0 = byi * 256, n0 = bxi * 128;
    const int bz = bzi >> sk_shift;
    const int ks = bzi & ((1 << sk_shift) - 1);
    const int kbeg = ks * ks_size;
    const int nsteps = ks_size >> 5;
    const int wm = (wave >> 1) * 64, wn = (wave & 1) * 64;
    const int fr = lane & 15, kslot = lane >> 4;
    const int srow = lane >> 2;

    const unsigned short* Ag = A + sA * bz + (long long)m0 * lda;
    const unsigned short* Bg = B + sB * bz + (long long)n0 * ldb;
    char* b0 = (char*)&SMEM[0][0];
    char* b1 = (char*)&SMEM[1][0];
    char* b2 = (char*)&SMEM[2][0];
    char* const sBase0 = b0;

    f32x4 acc[4][4] = {};

    auto STAGE = [&](char* base, int k0) {
        #pragma unroll
        for (int i = 0; i < 2; ++i) {
            const int r = (i * 8 + wave) * 16 + srow;
            const int qsrc = ((lane & 3) ^ ((r >> 1) & 3)) * 8;
            gload16(Ag + (long long)r * lda + k0 + qsrc, base + (i * 8 + wave) * 1024);
        }
        const int rB = wave * 16 + srow;
        const int qsB = ((lane & 3) ^ ((rB >> 1) & 3)) * 8;
        gload16(Bg + (long long)rB * ldb + k0 + qsB, base + 16384 + wave * 1024);
    };

    STAGE(b0, kbeg);
    STAGE(b1, kbeg + 32);
    asm volatile("s_waitcnt vmcnt(3)" ::: "memory");
    __builtin_amdgcn_s_barrier();
    __builtin_amdgcn_sched_barrier(0);

    for (int t = 0; t < nsteps; ++t) {
        const bool pf = (t + 2 < nsteps);
        if (pf) STAGE(b2, kbeg + (t + 2) * 32);

        f16x8 af[4], bf[4];
        #pragma unroll
        for (int q = 0; q < 4; ++q) {
            const int ra = wm + q * 16 + fr;
            const int rb = wn + q * 16 + fr;
            af[q] = *reinterpret_cast<const f16x8*>(b0 + ra * 64 + ((kslot ^ ((ra >> 1) & 3)) << 4));
            bf[q] = *reinterpret_cast<const f16x8*>(b0 + 16384 + rb * 64 + ((kslot ^ ((rb >> 1) & 3)) << 4));
        }
        __builtin_amdgcn_s_setprio(1);
        #pragma unroll
        for (int mi = 0; mi < 4; ++mi)
            #pragma unroll
            for (int ni = 0; ni < 4; ++ni)
                acc[mi][ni] = __builtin_amdgcn_mfma_f32_16x16x32_f16(af[mi], bf[ni], acc[mi][ni], 0, 0, 0);
        __builtin_amdgcn_s_setprio(0);

        if (t + 1 < nsteps) {
            if (pf) asm volatile("s_waitcnt vmcnt(3) lgkmcnt(0)" ::: "memory");
            else    asm volatile("s_waitcnt vmcnt(0) lgkmcnt(0)" ::: "memory");
            __builtin_amdgcn_s_barrier();
            __builtin_amdgcn_sched_barrier(0);
        }
        char* tmp = b0; b0 = b1; b1 = b2; b2 = tmp;
    }
    __syncthreads();

    unsigned short (*LT)[72] = reinterpret_cast<unsigned short(*)[72]>(sBase0 + wave * 2304);
    const int rb4 = (lane >> 4) * 4;

    if (EPI == 1) {
        #pragma unroll
        for (int mi = 0; mi < 4; ++mi) {
            const int rloc = wm + mi * 16 + rb4;
            #pragma unroll
            for (int ni = 0; ni < 4; ++ni) {
                const int c = n0 + wn + ni * 16 + fr;
                const float bv = bias[c];
                long long base = sC * bz + (long long)(m0 + rloc) * ldc + c;
                #pragma unroll
                for (int rr = 0; rr < 4; ++rr)
                    Cf[base + (long long)rr * ldc] = acc[mi][ni][rr] * scale + bv;
            }
        }
    } else {
        // EPI == 3: QKV. n-segment: [0,1024)=Q [1024,2048)=K [2048,3072)=V (wave-uniform)
        const int segw = (n0 + wn) >> 10;
        const int tokb = m0 + wm;
        const int bloc = tokb >> 12;
        const int nbb  = tokb & 4095;
        if (segw < 2) {
            unsigned short* pt = (segw == 0) ? qt : kt;
            #pragma unroll
            for (int ni = 0; ni < 4; ++ni) {
                const float bv = bias[n0 + wn + ni * 16 + fr];
                #pragma unroll
                for (int mi = 0; mi < 4; ++mi) {
                    u16x4 hv;
                    #pragma unroll
                    for (int rr = 0; rr < 4; ++rr)
                        hv[rr] = f2h(acc[mi][ni][rr] * scale + bv);
                    *reinterpret_cast<u16x4*>(&LT[fr][mi * 16 + rb4]) = hv;
                }
                #pragma unroll
                for (int q = 0; q < 4; ++q) {
                    const int f_l = q * 4 + (lane >> 4);
                    const int t0  = (lane & 15) * 4;
                    u16x4 hv = *reinterpret_cast<const u16x4*>(&LT[f_l][t0]);
                    const int lc = (n0 + wn + ni * 16 + f_l) & 1023;
                    *reinterpret_cast<u16x4*>(&pt[(long long)bloc * 4194304 +
                        (long long)lc * 4096 + nbb + t0]) = hv;
                }
            }
        } else {
            const int lc0 = (n0 + wn) & 1023;
            #pragma unroll
            for (int mi = 0; mi < 4; ++mi) {
                #pragma unroll
                for (int ni = 0; ni < 4; ++ni) {
                    const float bv = bias[n0 + wn + ni * 16 + fr];
                    #pragma unroll
                    for (int rr = 0; rr < 4; ++rr)
                        LT[rb4 + rr][ni * 16 + fr] = f2h(acc[mi][ni][rr] * scale + bv);
                }
                #pragma unroll
                for (int q = 0; q < 2; ++q) {
                    const int r_l = q * 8 + (lane >> 3);
                    const int f0  = (lane & 7) * 8;
                    u16x8 hv = *reinterpret_cast<const u16x8*>(&LT[r_l][f0]);
                    const int tok = nbb + mi * 16 + r_l;
                    *reinterpret_cast<u16x8*>(&vout[(long long)bloc * 4194304 +
                        (long long)tok * 1024 + lc0 + f0]) = hv;
                }
            }
        }
    }
}

// ======== kernel B: 256x256 tile, 8 waves (128x64 each), 2-buf = 64KB ========
// (measured-best for dots/PV in round 18)
// EPI: 2 f16 (LDS row-gather) | 4 f32 atomicAdd (split-K)
template<int EPI>
__global__ __launch_bounds__(512)
void gemm256(const unsigned short* __restrict__ A, const unsigned short* __restrict__ B,
             int sk_shift, int ks_size,
             long long lda, long long ldb,
             long long sA, long long sB, long long sC,
             float* __restrict__ Cf, unsigned short* __restrict__ Ch, long long ldc,
             float scale)
{
    __shared__ __align__(16) unsigned short SMEM[2][16384];   // 2 x 32KB

    const unsigned int gx = gridDim.x, gy = gridDim.y;
    const unsigned int lin = blockIdx.x + gx * (blockIdx.y + gy * blockIdx.z);
    const unsigned int nwg = gx * gy * gridDim.z;
    const unsigned int sw = (lin & 7u) * (nwg >> 3) + (lin >> 3);
    const int bxi = (int)(sw % gx);
    const int byi = (int)((sw / gx) % gy);
    const int bzi = (int)(sw / (gx * gy));

    const int tid  = threadIdx.x;
    const int wave = tid >> 6, lane = tid & 63;
    const int m0 = byi * 256, n0 = bxi * 256;
    const int bz = bzi >> sk_shift;
    const int ks = bzi & ((1 << sk_shift) - 1);
    const int kbeg = ks * ks_size;
    const int nsteps = ks_size >> 5;
    const int wm = (wave >> 2) * 128, wn = (wave & 3) * 64;
    const int fr = lane & 15, kslot = lane >> 4;
    const int srow = lane >> 2;

    const unsigned short* Ag = A + sA * bz + (long long)m0 * lda;
    const unsigned short* Bg = B + sB * bz + (long long)n0 * ldb;
    char* const sb0 = (char*)&SMEM[0][0];
    char* const sb1 = (char*)&SMEM[1][0];
    char* const sBase0 = sb0;

    f32x4 acc[8][4] = {};

    auto STAGE = [&](char* base, int k0) {
        #pragma unroll
        for (int i = 0; i < 2; ++i) {
            const int r = (i * 8 + wave) * 16 + srow;
            const int qsrc = ((lane & 3) ^ ((r >> 1) & 3)) * 8;
            gload16(Ag + (long long)r * lda + k0 + qsrc, base + (i * 8 + wave) * 1024);
            gload16(Bg + (long long)r * ldb + k0 + qsrc, base + 16384 + (i * 8 + wave) * 1024);
        }
    };

    STAGE(sb0, kbeg);
    asm volatile("s_waitcnt vmcnt(0)" ::: "memory");
    __builtin_amdgcn_s_barrier();
    __builtin_amdgcn_sched_barrier(0);

    for (int t = 0; t < nsteps; ++t) {
        char* const rd = (t & 1) ? sb1 : sb0;
        char* const wr = (t & 1) ? sb0 : sb1;
        if (t + 1 < nsteps) STAGE(wr, kbeg + (t + 1) * 32);

        f16x8 af[8], bf[4];
        #pragma unroll
        for (int q = 0; q < 8; ++q) {
            const int ra = wm + q * 16 + fr;
            af[q] = *reinterpret_cast<const f16x8*>(rd + ra * 64 + ((kslot ^ ((ra >> 1) & 3)) << 4));
        }
        #pragma unroll
        for (int q = 0; q < 4; ++q) {
            const int rb = wn + q * 16 + fr;
            bf[q] = *reinterpret_cast<const f16x8*>(rd + 16384 + rb * 64 + ((kslot ^ ((rb >> 1) & 3)) << 4));
        }
        __builtin_amdgcn_s_setprio(1);
        #pragma unroll
        for (int mi = 0; mi < 8; ++mi)
            #pragma unroll
            for (int ni = 0; ni < 4; ++ni)
                acc[mi][ni] = __builtin_amdgcn_mfma_f32_16x16x32_f16(af[mi], bf[ni], acc[mi][ni], 0, 0, 0);
        __builtin_amdgcn_s_setprio(0);

        if (t + 1 < nsteps) {
            asm volatile("s_waitcnt vmcnt(0) lgkmcnt(0)" ::: "memory");
            __builtin_amdgcn_s_barrier();
            __builtin_amdgcn_sched_barrier(0);
        }
    }
    __syncthreads();

    unsigned short (*LT)[72] = reinterpret_cast<unsigned short(*)[72]>(sBase0 + wave * 2304);
    const int rb4 = (lane >> 4) * 4;

    if (EPI == 4) {
        #pragma unroll
        for (int mi = 0; mi < 8; ++mi) {
            const int rloc = wm + mi * 16 + rb4;
            #pragma unroll
            for (int ni = 0; ni < 4; ++ni) {
                const int c = n0 + wn + ni * 16 + fr;
                long long base = sC * bz + (long long)(m0 + rloc) * ldc + c;
                #pragma unroll
                for (int rr = 0; rr < 4; ++rr)
                    atomicAdd(&Cf[base + (long long)rr * ldc], acc[mi][ni][rr] * scale);
            }
        }
    } else {
        // EPI == 2: f16 row-major out via LDS row-gather
        #pragma unroll
        for (int mi = 0; mi < 8; ++mi) {
            #pragma unroll
            for (int ni = 0; ni < 4; ++ni)
                #pragma unroll
                for (int rr = 0; rr < 4; ++rr)
                    LT[rb4 + rr][ni * 16 + fr] = f2h(acc[mi][ni][rr] * scale);
            #pragma unroll
            for (int q = 0; q < 2; ++q) {
                const int r_l = q * 8 + (lane >> 3);
                const int f0  = (lane & 7) * 8;
                u16x8 hv = *reinterpret_cast<const u16x8*>(&LT[r_l][f0]);
                long long base = sC * bz + (long long)(m0 + wm + mi * 16 + r_l) * ldc + (n0 + wn) + f0;
                *reinterpret_cast<u16x8*>(&Ch[base]) = hv;
            }
        }
    }
}

// ---------------- row softmax: 1024 fp32 -> 1024 fp16 ----------------
__global__ __launch_bounds__(256)
void softmax_rows_1024(const float* __restrict__ in, unsigned short* __restrict__ out)
{
    const int tid = threadIdx.x;
    const int wave = tid >> 6, lane = tid & 63;
    const long long rowoff = (long long)blockIdx.x * 1024;
    float4 v = reinterpret_cast<const float4*>(in + rowoff)[tid];

    float mx = fmaxf(fmaxf(v.x, v.y), fmaxf(v.z, v.w));
    #pragma unroll
    for (int o = 32; o > 0; o >>= 1) mx = fmaxf(mx, __shfl_xor(mx, o));
    __shared__ float rmax[4];
    if (lane == 0) rmax[wave] = mx;
    __syncthreads();
    mx = fmaxf(fmaxf(rmax[0], rmax[1]), fmaxf(rmax[2], rmax[3]));

    float e0 = expf(v.x - mx), e1 = expf(v.y - mx), e2 = expf(v.z - mx), e3 = expf(v.w - mx);
    float s = e0 + e1 + e2 + e3;
    #pragma unroll
    for (int o = 32; o > 0; o >>= 1) s += __shfl_xor(s, o);
    __shared__ float rsum[4];
    if (lane == 0) rsum[wave] = s;
    __syncthreads();
    s = rsum[0] + rsum[1] + rsum[2] + rsum[3];
    float inv = 1.0f / s;

    u16x4 o4;
    o4[0] = f2h(e0 * inv); o4[1] = f2h(e1 * inv);
    o4[2] = f2h(e2 * inv); o4[3] = f2h(e3 * inv);
    *reinterpret_cast<u16x4*>(out + rowoff + tid * 4) = o4;
}

extern "C" void kernel_launch(void* const* d_in, const int* in_sizes, int n_in,
                              void* d_out, int out_size, void* d_ws, size_t ws_size,
                              hipStream_t stream)
{
    const float* x    = (const float*)d_in[0];  // (4,4096,1024)
    const float* Wqkv = (const float*)d_in[1];  // (1024,3072)
    const float* bqkv = (const float*)d_in[2];  // (3072,)
    const float* Wout = (const float*)d_in[3];  // (1024,1024)
    const float* bout = (const float*)d_in[4];  // (1024,)
    float* out = (float*)d_out;                 // (4,4096,1024) fp32

    // ---- workspace (peak 201,326,592 B == proven-safe) ----
    char* ws = (char*)d_ws;
    unsigned short* xf   = (unsigned short*)(ws);              // 33,554,432 (4,4096,1024) f16
    unsigned short* Wq16 = (unsigned short*)(ws + 33554432);   //  6,291,456 (3072,1024) f16 W^T
    unsigned short* Wo16 = (unsigned short*)(ws + 39845888);   //  2,097,152 (1024,1024) f16 W^T
    unsigned short* Qt   = (unsigned short*)(ws + 41943040);   // 33,554,432 (4,1024,4096) f16
    unsigned short* Kt   = (unsigned short*)(ws + 75497472);   // 33,554,432
    unsigned short* V    = (unsigned short*)(ws + 109051904);  // 33,554,432 (4,4096,1024) f16
    float*          dots = (float*)(ws + 142606336);           // 16,777,216 (4,1024,1024) f32
    unsigned short* attn = (unsigned short*)(ws + 159383552);  //  8,388,608 (4,1024,1024) f16
    unsigned short* omid = (unsigned short*)(ws + 167772160);  // 33,554,432 (4,1024,4096) f16

    // dots accumulated atomically (split-K) -> zero first
    zero_f32<<<dim3(2048), dim3(256), 0, stream>>>(dots, 1048576);

    // converts
    cvt_f32_f16<<<dim3(2048), dim3(256), 0, stream>>>(x, xf, 2097152);
    transpose_cvt<<<dim3(48, 16), dim3(256), 0, stream>>>(Wqkv, Wq16, 1024, 3072);
    transpose_cvt<<<dim3(16, 16), dim3(256), 0, stream>>>(Wout, Wo16, 1024, 1024);

    // 1) qkv = x @ Wqkv + bqkv -> Q^T, K^T (transposed f16) + V f16  (256x128 kernel)
    gemm_a<3><<<dim3(24, 64, 1), dim3(512), 0, stream>>>(
        xf, Wq16, 0, 1024,
        1024LL, 1024LL, 0LL, 0LL, 0LL,
        nullptr, nullptr, 0LL, bqkv, 1.0f,
        Qt, Kt, V);

    // 2) dots[b] = 0.125 * Q^T K  (M=N=1024, K=4096), split-K x4, atomic f32 (256x256 2-buf)
    gemm256<4><<<dim3(4, 4, 16), dim3(512), 0, stream>>>(
        Qt, Kt, 2, 1024,
        4096LL, 4096LL, 4194304LL, 4194304LL, 1048576LL,
        dots, nullptr, 1024LL, 0.125f);

    // 3) softmax over g -> attn f16
    softmax_rows_1024<<<dim3(4096), dim3(256), 0, stream>>>(dots, attn);

    // 4) omid[b][f][n] = attn[b] @ V[b]^T  (M=1024, N=4096, K=1024) -> f16 (256x256 2-buf)
    gemm256<2><<<dim3(16, 4, 4), dim3(512), 0, stream>>>(
        attn, V, 0, 1024,
        1024LL, 1024LL, 1048576LL, 4194304LL, 4194304LL,
        nullptr, omid, 4096LL, 1.0f);

    // 5) out = omid_flat(16384x1024) @ Wout^T + bout -> f32 (256x128 kernel)
    gemm_a<1><<<dim3(8, 64, 1), dim3(512), 0, stream>>>(
        omid, Wo16, 0, 1024,
        1024LL, 1024LL, 0LL, 0LL, 0LL,
        out, nullptr, 1024LL, bout, 1.0f,
        nullptr, nullptr, nullptr);
}

// Round 20
// 301.223 us; speedup vs baseline: 1.0260x; 1.0260x over previous
//
#include <hip/hip_runtime.h>
#include <hip/hip_bf16.h>

typedef _Float16 f16x8 __attribute__((ext_vector_type(8)));
typedef float f32x4 __attribute__((ext_vector_type(4)));
typedef unsigned short u16x4 __attribute__((ext_vector_type(4)));
typedef unsigned short u16x8 __attribute__((ext_vector_type(8)));

__device__ __forceinline__ unsigned short f2h(float f) {
    _Float16 h = (_Float16)f;
    union { _Float16 h; unsigned short u; } v; v.h = h;
    return v.u;
}

// async global->LDS, 16B per lane. LDS dest = wave-uniform base + lane*16.
__device__ __forceinline__ void gload16(const void* g, void* s) {
    __builtin_amdgcn_global_load_lds((const __attribute__((address_space(1))) void*)g,
                                     (__attribute__((address_space(3))) void*)s, 16, 0, 0);
}

// ---------------- zero fp32 buffer ----------------
__global__ __launch_bounds__(256)
void zero_f32(float* __restrict__ p, int n4) {
    int i = blockIdx.x * 256 + threadIdx.x, st = gridDim.x * 256;
    for (; i < n4; i += st)
        reinterpret_cast<float4*>(p)[i] = make_float4(0.f, 0.f, 0.f, 0.f);
}

// ---------------- fp32 -> fp16 convert ----------------
__global__ __launch_bounds__(256)
void cvt_f32_f16(const float* __restrict__ in, unsigned short* __restrict__ out, int n8) {
    int i = blockIdx.x * 256 + threadIdx.x, st = gridDim.x * 256;
    for (; i < n8; i += st) {
        float4 v0 = reinterpret_cast<const float4*>(in)[2 * i];
        float4 v1 = reinterpret_cast<const float4*>(in)[2 * i + 1];
        float a[8] = {v0.x, v0.y, v0.z, v0.w, v1.x, v1.y, v1.z, v1.w};
        u16x8 h;
        #pragma unroll
        for (int j = 0; j < 8; ++j) h[j] = f2h(a[j]);
        reinterpret_cast<u16x8*>(out)[i] = h;
    }
}

// ---------------- W (R x C fp32) -> W^T fp16 (C x R) ----------------
__global__ __launch_bounds__(256)
void transpose_cvt(const float* __restrict__ in, unsigned short* __restrict__ ot,
                   int R, int C) {
    __shared__ float T[64][65];
    const int r0 = blockIdx.y * 64, c0 = blockIdx.x * 64;
    const int t = threadIdx.x;
    const int lr = t >> 2, lcq = (t & 3) * 16;
    #pragma unroll
    for (int q = 0; q < 4; ++q) {
        float4 v = *reinterpret_cast<const float4*>(&in[(long long)(r0 + lr) * C + c0 + lcq + q * 4]);
        T[lr][lcq + q * 4 + 0] = v.x; T[lr][lcq + q * 4 + 1] = v.y;
        T[lr][lcq + q * 4 + 2] = v.z; T[lr][lcq + q * 4 + 3] = v.w;
    }
    __syncthreads();
    const int oc = t >> 2, orq = (t & 3) * 16;
    #pragma unroll
    for (int q = 0; q < 4; ++q) {
        u16x4 hv;
        #pragma unroll
        for (int j = 0; j < 4; ++j) hv[j] = f2h(T[orq + q * 4 + j][oc]);
        long long o = (long long)(c0 + oc) * R + r0 + orq + q * 4;
        *reinterpret_cast<u16x4*>(&ot[o]) = hv;
    }
}

// ======== unified GEMM: 256x256 tile, 8 waves (128x64 each), 2-buf = 64KB ========
// C = scale * (A @ B^T) + bias. A[M][K] lda, Bt[N][K] ldb, k-contiguous fp16.
// BM=BN=256, BK=32, 512 thr / 8 waves; wave (wm=(w>>2)*128, wn=(w&3)*64) owns 128x64:
// 12 ds_read_b128 feed 32 MFMAs (32 FLOP/LDS-byte). Double-buffered LDS; stage for
// t+1 issued at TOP of step t (latency elapses under ds_read+MFMA), then
// vmcnt(0)+lgkmcnt(0)+barrier at step end. T2 slot-swizzle both sides; T1 XCD swizzle.
// Best measured full-pipeline config (round 18: 301.9us).
// EPI: 1 f32+bias | 2 f16 (LDS row-gather) | 3 QKV (Q^T,K^T LDS transpose + V row-gather)
//      4 f32 atomicAdd (split-K).  blockIdx.z(logical) = (batch<<sk_shift)|ks.
template<int EPI>
__global__ __launch_bounds__(512)
void gemm256(const unsigned short* __restrict__ A, const unsigned short* __restrict__ B,
             int sk_shift, int ks_size,
             long long lda, long long ldb,
             long long sA, long long sB, long long sC,
             float* __restrict__ Cf, unsigned short* __restrict__ Ch, long long ldc,
             const float* __restrict__ bias, float scale,
             unsigned short* __restrict__ qt, unsigned short* __restrict__ kt,
             unsigned short* __restrict__ vout)
{
    __shared__ __align__(16) unsigned short SMEM[2][16384];   // 2 x 32KB

    // ---- bijective XCD swizzle (nwg % 8 == 0 for all launches) ----
    const unsigned int gx = gridDim.x, gy = gridDim.y;
    const unsigned int lin = blockIdx.x + gx * (blockIdx.y + gy * blockIdx.z);
    const unsigned int nwg = gx * gy * gridDim.z;
    const unsigned int sw = (lin & 7u) * (nwg >> 3) + (lin >> 3);
    const int bxi = (int)(sw % gx);
    const int byi = (int)((sw / gx) % gy);
    const int bzi = (int)(sw / (gx * gy));

    const int tid  = threadIdx.x;
    const int wave = tid >> 6, lane = tid & 63;
    const int m0 = byi * 256, n0 = bxi * 256;
    const int bz = bzi >> sk_shift;
    const int ks = bzi & ((1 << sk_shift) - 1);
    const int kbeg = ks * ks_size;
    const int nsteps = ks_size >> 5;
    const int wm = (wave >> 2) * 128, wn = (wave & 3) * 64;
    const int fr = lane & 15, kslot = lane >> 4;
    const int srow = lane >> 2;

    const unsigned short* Ag = A + sA * bz + (long long)m0 * lda;
    const unsigned short* Bg = B + sB * bz + (long long)n0 * ldb;
    char* const sb0 = (char*)&SMEM[0][0];
    char* const sb1 = (char*)&SMEM[1][0];
    char* const sBase0 = sb0;

    f32x4 acc[8][4] = {};

    // stage K-chunk k0: A 256x32 at +0, B 256x32 at +16384 (4 loads/thread)
    auto STAGE = [&](char* base, int k0) {
        #pragma unroll
        for (int i = 0; i < 2; ++i) {
            const int r = (i * 8 + wave) * 16 + srow;
            const int qsrc = ((lane & 3) ^ ((r >> 1) & 3)) * 8;
            gload16(Ag + (long long)r * lda + k0 + qsrc, base + (i * 8 + wave) * 1024);
            gload16(Bg + (long long)r * ldb + k0 + qsrc, base + 16384 + (i * 8 + wave) * 1024);
        }
    };

    STAGE(sb0, kbeg);
    asm volatile("s_waitcnt vmcnt(0)" ::: "memory");
    __builtin_amdgcn_s_barrier();
    __builtin_amdgcn_sched_barrier(0);

    for (int t = 0; t < nsteps; ++t) {
        char* const rd = (t & 1) ? sb1 : sb0;
        char* const wr = (t & 1) ? sb0 : sb1;
        // issue next-tile stage FIRST: its HBM latency elapses under this step's
        // ds_read + MFMA phase, so the end-of-step vmcnt(0) waits little.
        if (t + 1 < nsteps) STAGE(wr, kbeg + (t + 1) * 32);

        f16x8 af[8], bf[4];
        #pragma unroll
        for (int q = 0; q < 8; ++q) {
            const int ra = wm + q * 16 + fr;
            af[q] = *reinterpret_cast<const f16x8*>(rd + ra * 64 + ((kslot ^ ((ra >> 1) & 3)) << 4));
        }
        #pragma unroll
        for (int q = 0; q < 4; ++q) {
            const int rb = wn + q * 16 + fr;
            bf[q] = *reinterpret_cast<const f16x8*>(rd + 16384 + rb * 64 + ((kslot ^ ((rb >> 1) & 3)) << 4));
        }
        __builtin_amdgcn_s_setprio(1);
        #pragma unroll
        for (int mi = 0; mi < 8; ++mi)
            #pragma unroll
            for (int ni = 0; ni < 4; ++ni)
                acc[mi][ni] = __builtin_amdgcn_mfma_f32_16x16x32_f16(af[mi], bf[ni], acc[mi][ni], 0, 0, 0);
        __builtin_amdgcn_s_setprio(0);

        if (t + 1 < nsteps) {
            // wr fully landed (vmcnt) AND all waves' ds_reads of rd done (lgkm):
            // next step reads wr and step t+2 will overwrite rd.
            asm volatile("s_waitcnt vmcnt(0) lgkmcnt(0)" ::: "memory");
            __builtin_amdgcn_s_barrier();
            __builtin_amdgcn_sched_barrier(0);
        }
    }
    __syncthreads();   // all waves done with LDS -> safe to overlay epilogue staging

    // per-wave epilogue staging overlaying the (dead) buffers:
    //   row-gather:    LT  [16][72]  (2304B/wave, 18.4KB total)
    //   Q/K transpose: LT2 [16][136] (4352B/wave, 34.8KB total <= 64KB)
    unsigned short (*LT)[72]   = reinterpret_cast<unsigned short(*)[72]>(sBase0 + wave * 2304);
    unsigned short (*LT2)[136] = reinterpret_cast<unsigned short(*)[136]>(sBase0 + wave * 4352);

    // ---- epilogues. acc frag: D[row=(lane>>4)*4+rr][col=lane&15] ----
    const int rb4 = (lane >> 4) * 4;

    if (EPI == 1 || EPI == 4) {
        #pragma unroll
        for (int mi = 0; mi < 8; ++mi) {
            const int rloc = wm + mi * 16 + rb4;
            #pragma unroll
            for (int ni = 0; ni < 4; ++ni) {
                const int c = n0 + wn + ni * 16 + fr;
                const float bv = (EPI == 1) ? bias[c] : 0.0f;
                long long base = sC * bz + (long long)(m0 + rloc) * ldc + c;
                #pragma unroll
                for (int rr = 0; rr < 4; ++rr) {
                    float v = acc[mi][ni][rr] * scale + bv;
                    if (EPI == 1) Cf[base + (long long)rr * ldc] = v;
                    else          atomicAdd(&Cf[base + (long long)rr * ldc], v);
                }
            }
        }
    } else if (EPI == 2) {
        // f16 row-major out, LDS row-gather: per mi stage 16 rows x 64 cols, store 16B/lane
        #pragma unroll
        for (int mi = 0; mi < 8; ++mi) {
            #pragma unroll
            for (int ni = 0; ni < 4; ++ni)
                #pragma unroll
                for (int rr = 0; rr < 4; ++rr)
                    LT[rb4 + rr][ni * 16 + fr] = f2h(acc[mi][ni][rr] * scale);
            #pragma unroll
            for (int q = 0; q < 2; ++q) {
                const int r_l = q * 8 + (lane >> 3);
                const int f0  = (lane & 7) * 8;
                u16x8 hv = *reinterpret_cast<const u16x8*>(&LT[r_l][f0]);
                long long base = sC * bz + (long long)(m0 + wm + mi * 16 + r_l) * ldc + (n0 + wn) + f0;
                *reinterpret_cast<u16x8*>(&Ch[base]) = hv;
            }
        }
    } else {
        // EPI == 3: QKV. Block-uniform segment by n: [0,1024)=Q [1024,2048)=K [2048,3072)=V
        const int segw = (n0 + wn) >> 10;
        const int tokb = m0 + wm;            // wave token base (128 tokens, one batch)
        const int bloc = tokb >> 12;
        const int nbb  = tokb & 4095;
        if (segw < 2) {
            // Q^T / K^T: per ni stage transposed 16 feats x 128 tokens, 16B/lane stores
            unsigned short* pt = (segw == 0) ? qt : kt;
            #pragma unroll
            for (int ni = 0; ni < 4; ++ni) {
                const float bv = bias[n0 + wn + ni * 16 + fr];
                #pragma unroll
                for (int mi = 0; mi < 8; ++mi) {
                    u16x4 hv;
                    #pragma unroll
                    for (int rr = 0; rr < 4; ++rr)
                        hv[rr] = f2h(acc[mi][ni][rr] * scale + bv);
                    *reinterpret_cast<u16x4*>(&LT2[fr][mi * 16 + rb4]) = hv;
                }
                #pragma unroll
                for (int q = 0; q < 4; ++q) {
                    const int f_l = q * 4 + (lane >> 4);
                    const int t0  = (lane & 15) * 8;
                    u16x8 hv = *reinterpret_cast<const u16x8*>(&LT2[f_l][t0]);
                    const int lc = (n0 + wn + ni * 16 + f_l) & 1023;
                    *reinterpret_cast<u16x8*>(&pt[(long long)bloc * 4194304 +
                        (long long)lc * 4096 + nbb + t0]) = hv;
                }
            }
        } else {
            // V: row-major f16 with bias, LDS row-gather
            const int lc0 = (n0 + wn) & 1023;
            #pragma unroll
            for (int mi = 0; mi < 8; ++mi) {
                #pragma unroll
                for (int ni = 0; ni < 4; ++ni) {
                    const float bv = bias[n0 + wn + ni * 16 + fr];
                    #pragma unroll
                    for (int rr = 0; rr < 4; ++rr)
                        LT[rb4 + rr][ni * 16 + fr] = f2h(acc[mi][ni][rr] * scale + bv);
                }
                #pragma unroll
                for (int q = 0; q < 2; ++q) {
                    const int r_l = q * 8 + (lane >> 3);
                    const int f0  = (lane & 7) * 8;
                    u16x8 hv = *reinterpret_cast<const u16x8*>(&LT[r_l][f0]);
                    const int tok = nbb + mi * 16 + r_l;
                    *reinterpret_cast<u16x8*>(&vout[(long long)bloc * 4194304 +
                        (long long)tok * 1024 + lc0 + f0]) = hv;
                }
            }
        }
    }
}

// ---------------- row softmax: 1024 fp32 -> 1024 fp16 ----------------
__global__ __launch_bounds__(256)
void softmax_rows_1024(const float* __restrict__ in, unsigned short* __restrict__ out)
{
    const int tid = threadIdx.x;
    const int wave = tid >> 6, lane = tid & 63;
    const long long rowoff = (long long)blockIdx.x * 1024;
    float4 v = reinterpret_cast<const float4*>(in + rowoff)[tid];

    float mx = fmaxf(fmaxf(v.x, v.y), fmaxf(v.z, v.w));
    #pragma unroll
    for (int o = 32; o > 0; o >>= 1) mx = fmaxf(mx, __shfl_xor(mx, o));
    __shared__ float rmax[4];
    if (lane == 0) rmax[wave] = mx;
    __syncthreads();
    mx = fmaxf(fmaxf(rmax[0], rmax[1]), fmaxf(rmax[2], rmax[3]));

    float e0 = expf(v.x - mx), e1 = expf(v.y - mx), e2 = expf(v.z - mx), e3 = expf(v.w - mx);
    float s = e0 + e1 + e2 + e3;
    #pragma unroll
    for (int o = 32; o > 0; o >>= 1) s += __shfl_xor(s, o);
    __shared__ float rsum[4];
    if (lane == 0) rsum[wave] = s;
    __syncthreads();
    s = rsum[0] + rsum[1] + rsum[2] + rsum[3];
    float inv = 1.0f / s;

    u16x4 o4;
    o4[0] = f2h(e0 * inv); o4[1] = f2h(e1 * inv);
    o4[2] = f2h(e2 * inv); o4[3] = f2h(e3 * inv);
    *reinterpret_cast<u16x4*>(out + rowoff + tid * 4) = o4;
}

extern "C" void kernel_launch(void* const* d_in, const int* in_sizes, int n_in,
                              void* d_out, int out_size, void* d_ws, size_t ws_size,
                              hipStream_t stream)
{
    const float* x    = (const float*)d_in[0];  // (4,4096,1024)
    const float* Wqkv = (const float*)d_in[1];  // (1024,3072)
    const float* bqkv = (const float*)d_in[2];  // (3072,)
    const float* Wout = (const float*)d_in[3];  // (1024,1024)
    const float* bout = (const float*)d_in[4];  // (1024,)
    float* out = (float*)d_out;                 // (4,4096,1024) fp32

    // ---- workspace (peak 201,326,592 B == proven-safe) ----
    char* ws = (char*)d_ws;
    unsigned short* xf   = (unsigned short*)(ws);              // 33,554,432 (4,4096,1024) f16
    unsigned short* Wq16 = (unsigned short*)(ws + 33554432);   //  6,291,456 (3072,1024) f16 W^T
    unsigned short* Wo16 = (unsigned short*)(ws + 39845888);   //  2,097,152 (1024,1024) f16 W^T
    unsigned short* Qt   = (unsigned short*)(ws + 41943040);   // 33,554,432 (4,1024,4096) f16
    unsigned short* Kt   = (unsigned short*)(ws + 75497472);   // 33,554,432
    unsigned short* V    = (unsigned short*)(ws + 109051904);  // 33,554,432 (4,4096,1024) f16
    float*          dots = (float*)(ws + 142606336);           // 16,777,216 (4,1024,1024) f32
    unsigned short* attn = (unsigned short*)(ws + 159383552);  //  8,388,608 (4,1024,1024) f16
    unsigned short* omid = (unsigned short*)(ws + 167772160);  // 33,554,432 (4,1024,4096) f16

    // dots accumulated atomically (split-K) -> zero first
    zero_f32<<<dim3(2048), dim3(256), 0, stream>>>(dots, 1048576);

    // converts
    cvt_f32_f16<<<dim3(2048), dim3(256), 0, stream>>>(x, xf, 2097152);
    transpose_cvt<<<dim3(48, 16), dim3(256), 0, stream>>>(Wqkv, Wq16, 1024, 3072);
    transpose_cvt<<<dim3(16, 16), dim3(256), 0, stream>>>(Wout, Wo16, 1024, 1024);

    // 1) qkv = x @ Wqkv + bqkv -> Q^T, K^T (transposed f16) + V f16  (M=16384, N=3072)
    gemm256<3><<<dim3(12, 64, 1), dim3(512), 0, stream>>>(
        xf, Wq16, 0, 1024,
        1024LL, 1024LL, 0LL, 0LL, 0LL,
        nullptr, nullptr, 0LL, bqkv, 1.0f,
        Qt, Kt, V);

    // 2) dots[b] = 0.125 * Q^T K  (M=N=1024, K=4096), split-K x4, atomic f32
    gemm256<4><<<dim3(4, 4, 16), dim3(512), 0, stream>>>(
        Qt, Kt, 2, 1024,
        4096LL, 4096LL, 4194304LL, 4194304LL, 1048576LL,
        dots, nullptr, 1024LL, nullptr, 0.125f,
        nullptr, nullptr, nullptr);

    // 3) softmax over g -> attn f16
    softmax_rows_1024<<<dim3(4096), dim3(256), 0, stream>>>(dots, attn);

    // 4) omid[b][f][n] = attn[b] @ V[b]^T  (M=1024, N=4096, K=1024) -> f16
    gemm256<2><<<dim3(16, 4, 4), dim3(512), 0, stream>>>(
        attn, V, 0, 1024,
        1024LL, 1024LL, 1048576LL, 4194304LL, 4194304LL,
        nullptr, omid, 4096LL, nullptr, 1.0f,
        nullptr, nullptr, nullptr);

    // 5) out = omid_flat(16384x1024) @ Wout^T + bout -> f32
    gemm256<1><<<dim3(4, 64, 1), dim3(512), 0, stream>>>(
        omid, Wo16, 0, 1024,
        1024LL, 1024LL, 0LL, 0LL, 0LL,
        out, nullptr, 1024LL, bout, 1.0f,
        nullptr, nullptr, nullptr);
}